// Round 14
// baseline (308.361 us; speedup 1.0000x reference)
//
#include <hip/hip_runtime.h>

#define DIM 256
#define RPB 32            // dst rows per bucket
#define LOG_RPB 5
#define NG 8              // XCD groups: g=(e>>8)&7 == blockIdx&7 (grid%8==0)
#define CAP 128           // slab capacity per (g,bucket) cell; Poisson(<=40) -> 14 sigma
#define BCAP 512          // edges per bucket; Poisson(<=320) -> 10.7 sigma
#define PC_B 3072         // place_conv blocks; 384 groups of 8; group%3==0 -> place (1024)

typedef float f32x4 __attribute__((ext_vector_type(4)));
typedef unsigned int u32;
typedef unsigned short u16;

__device__ __forceinline__ u16 f32_to_bf16_rne(float f) {
    u32 u = __float_as_uint(f);
    return (u16)((u + 0x7FFFu + ((u >> 16) & 1u)) >> 16);
}

// ---------- fused slab placement (XCD-local) + f32->bf16 convert (round-13, proven) ----

__global__ void place_conv(const int* __restrict__ sA, const int* __restrict__ dA,
                           const int* __restrict__ sB, const int* __restrict__ dB,
                           int* __restrict__ cnt, u32* __restrict__ binned,
                           int TBc, int NBA_, int E1, int Etot,
                           const float* __restrict__ xin, u16* __restrict__ xbf,
                           long long n4) {
    int grp = (int)blockIdx.x >> 3;                        // group of 8 blocks
    int lane8 = (int)blockIdx.x & 7;
    if (grp % 3 == 0) {
        // ---- place role: 1/3 of blocks (1024) ----
        int sub = (grp / 3) * 8 + lane8;                   // role-local rank, sub&7 == XCD
        int nplace = ((int)gridDim.x / 24) * 8;            // 1024
        int stride = nplace * (int)blockDim.x;             // 262144; >>8 %8==0: g invariant
        for (int e = sub * (int)blockDim.x + (int)threadIdx.x; e < Etot; e += stride) {
            int g = (e >> 8) & (NG - 1);                   // == sub&7 == this XCD
            int s, d, b;
            if (e < E1) {
                s = __builtin_nontemporal_load(sA + e);
                d = __builtin_nontemporal_load(dA + e);
                b = d >> LOG_RPB;
            } else {
                int e2 = e - E1;
                s = __builtin_nontemporal_load(sB + e2);
                d = __builtin_nontemporal_load(dB + e2);
                b = NBA_ + (d >> LOG_RPB);
            }
            int cell = g * TBc + b;
            int old = atomicAdd(&cnt[cell], 1);            // XCD-private counter
            if (old < CAP)
                binned[(long long)cell * CAP + old] = ((u32)s << LOG_RPB) | (u32)(d & (RPB - 1));
        }
    } else {
        // ---- convert role: 2/3 of blocks (2048): x_paper f32 -> bf16 ----
        int cg = grp - (grp / 3 + 1);                      // convert-local group index
        int sub = cg * 8 + lane8;
        long long nconv = ((long long)gridDim.x / 24) * 16;   // 2048
        long long stride = nconv * blockDim.x;
        for (long long i = (long long)sub * blockDim.x + threadIdx.x; i < n4; i += stride) {
            f32x4 v = __builtin_nontemporal_load((const f32x4*)xin + i);
            ushort4 o;
            o.x = f32_to_bf16_rne(v.x); o.y = f32_to_bf16_rne(v.y);
            o.z = f32_to_bf16_rne(v.z); o.w = f32_to_bf16_rne(v.w);
            *((ushort4*)xbf + i) = o;                      // re-read by gather1: cached
        }
    }
}

// ---------- gather hop: one block per bucket; TWO rows per wave in flight ----------
// Pairing rows (rr, rr+4) doubles outstanding loads per wave (2*BATCH before the
// first waitcnt). ALL vv defs/uses unconditional with static indices (rule #20);
// sed zero-initialized so every clamped index yields a valid row id; masked-fma
// commit; conditional SCALAR stores only.

template <int BATCH, bool DBF>
__global__ void __launch_bounds__(256)
gather_hop(const u32* __restrict__ binned, const int* __restrict__ cnt,
           const u16* __restrict__ xv, void* __restrict__ outv,
           int TBc, int bucket_base, int n) {
    __shared__ int sed[BCAP];          // src ids, grouped by local row
    __shared__ int rp[RPB + 1];        // local row offsets into sed
    __shared__ int c[RPB];
    __shared__ int cur[RPB];

    int tid = (int)threadIdx.x;
    int b = bucket_base + (int)blockIdx.x;

    // --- phase 1: zero sed (clamp-safety) + histogram over the 8 XCD slabs ---
    for (int i = tid; i < BCAP; i += 256) sed[i] = 0;
    if (tid < RPB) c[tid] = 0;
    __syncthreads();
#pragma unroll
    for (int g = 0; g < NG; ++g) {
        int cell = g * TBc + b;
        int m = cnt[cell]; m = (m < CAP) ? m : CAP;
        long long base = (long long)cell * CAP;
        for (int i = tid; i < m; i += 256)
            atomicAdd(&c[binned[base + i] & (RPB - 1)], 1);
    }
    __syncthreads();
    // --- phase 2: tiny serial prefix (32 entries) ---
    if (tid == 0) {
        int run = 0;
        for (int r = 0; r < RPB; ++r) { cur[r] = run; rp[r] = run; run += c[r]; }
        rp[RPB] = run;
    }
    __syncthreads();
    // --- phase 3: place src ids grouped by local row (native LDS int atomics) ---
#pragma unroll
    for (int g = 0; g < NG; ++g) {
        int cell = g * TBc + b;
        int m = cnt[cell]; m = (m < CAP) ? m : CAP;
        long long base = (long long)cell * CAP;
        for (int i = tid; i < m; i += 256) {
            u32 e = binned[base + i];
            int pos = atomicAdd(&cur[e & (RPB - 1)], 1);
            sed[pos] = (int)(e >> LOG_RPB);
        }
    }
    __syncthreads();

    // --- phase 4: wave w owns rows {w, w+4, ..., w+28}; process PAIRS (rr, rr+4) ---
    int lane = tid & 63, w = tid >> 6;
    int row0base = (int)blockIdx.x * RPB;
    for (int rr = w; rr < RPB; rr += 8) {
        int ra = rr, rb = rr + 4;                         // both < RPB
        int beg0 = rp[ra], end0 = rp[ra + 1];             // wave-uniform
        int beg1 = rp[rb], end1 = rp[rb + 1];
        int it0 = (end0 - beg0 + BATCH - 1) / BATCH;
        int it1 = (end1 - beg1 + BATCH - 1) / BATCH;
        int iters = (it0 > it1) ? it0 : it1;
        float a0x = 0.f, a0y = 0.f, a0z = 0.f, a0w = 0.f;
        float a1x = 0.f, a1y = 0.f, a1z = 0.f, a1w = 0.f;
        int i0 = beg0, i1 = beg1;
        for (int it = 0; it < iters; ++it) {
            int m0 = end0 - i0; m0 = (m0 < 0) ? 0 : ((m0 > BATCH) ? BATCH : m0);
            int m1 = end1 - i1; m1 = (m1 < 0) ? 0 : ((m1 > BATCH) ? BATCH : m1);
            int base0 = (m0 > 0) ? i0 : ((end0 > 0) ? end0 - 1 : 0);   // always valid sed idx
            int base1 = (m1 > 0) ? i1 : ((end1 > 0) ? end1 - 1 : 0);
            uint2 v0[BATCH], v1[BATCH];
#pragma unroll
            for (int j = 0; j < BATCH; ++j) {             // issue 2*BATCH loads back-to-back
                int j0 = (j < m0) ? j : ((m0 > 0) ? m0 - 1 : 0);
                int j1 = (j < m1) ? j : ((m1 > 0) ? m1 - 1 : 0);
                int s0 = sed[base0 + j0];                 // LDS broadcast (wave-uniform)
                int s1 = sed[base1 + j1];
                v0[j] = *((const uint2*)(xv + (long long)s0 * DIM) + lane);
                v1[j] = *((const uint2*)(xv + (long long)s1 * DIM) + lane);
            }
#pragma unroll
            for (int j = 0; j < BATCH; ++j) {             // commit: all uses unconditional
                float k0 = (j < m0) ? 1.0f : 0.0f;
                float k1 = (j < m1) ? 1.0f : 0.0f;
                a0x = fmaf(k0, __uint_as_float(v0[j].x << 16), a0x);
                a0y = fmaf(k0, __uint_as_float(v0[j].x & 0xFFFF0000u), a0y);
                a0z = fmaf(k0, __uint_as_float(v0[j].y << 16), a0z);
                a0w = fmaf(k0, __uint_as_float(v0[j].y & 0xFFFF0000u), a0w);
                a1x = fmaf(k1, __uint_as_float(v1[j].x << 16), a1x);
                a1y = fmaf(k1, __uint_as_float(v1[j].x & 0xFFFF0000u), a1y);
                a1z = fmaf(k1, __uint_as_float(v1[j].y << 16), a1z);
                a1w = fmaf(k1, __uint_as_float(v1[j].y & 0xFFFF0000u), a1w);
            }
            i0 += BATCH; i1 += BATCH;
        }
        a0x = fmaxf(a0x, 0.f); a0y = fmaxf(a0y, 0.f); a0z = fmaxf(a0z, 0.f); a0w = fmaxf(a0w, 0.f);
        a1x = fmaxf(a1x, 0.f); a1y = fmaxf(a1y, 0.f); a1z = fmaxf(a1z, 0.f); a1w = fmaxf(a1w, 0.f);
        int row0 = row0base + ra, row1 = row0base + rb;
        if (DBF) {
            ushort4 o0, o1;
            o0.x = f32_to_bf16_rne(a0x); o0.y = f32_to_bf16_rne(a0y);
            o0.z = f32_to_bf16_rne(a0z); o0.w = f32_to_bf16_rne(a0w);
            o1.x = f32_to_bf16_rne(a1x); o1.y = f32_to_bf16_rne(a1y);
            o1.z = f32_to_bf16_rne(a1z); o1.w = f32_to_bf16_rne(a1w);
            if (row0 < n) *((ushort4*)outv + (long long)row0 * (DIM / 4) + lane) = o0;
            if (row1 < n) *((ushort4*)outv + (long long)row1 * (DIM / 4) + lane) = o1;
        } else {
            f32x4 o0 = { a0x, a0y, a0z, a0w };
            f32x4 o1 = { a1x, a1y, a1z, a1w };
            if (row0 < n)
                __builtin_nontemporal_store(o0, (f32x4*)outv + (long long)row0 * (DIM / 4) + lane);
            if (row1 < n)
                __builtin_nontemporal_store(o1, (f32x4*)outv + (long long)row1 * (DIM / 4) + lane);
        }
    }
}

// ---------- host ----------

extern "C" void kernel_launch(void* const* d_in, const int* in_sizes, int n_in,
                              void* d_out, int out_size, void* d_ws, size_t ws_size,
                              hipStream_t stream) {
    const float* x_paper = (const float*)d_in[0];
    const int* e_pa_src = (const int*)d_in[2];
    const int* e_pa_dst = (const int*)d_in[3];
    const int* e_ap_src = (const int*)d_in[4];
    const int* e_ap_dst = (const int*)d_in[5];

    const int nA = in_sizes[1] / DIM;         // 100000 authors (hop-1 dst, mean deg 10)
    const int nB = in_sizes[0] / DIM;         // 200000 papers  (hop-2 dst, mean deg 5)
    const int E1 = in_sizes[2];               // 1000000 (paper->author)
    const int E2 = in_sizes[4];               // 1000000 (author->paper)
    const int Etot = E1 + E2;

    const int NBA = (nA + RPB - 1) / RPB;     // 3125
    const int NBB = (nB + RPB - 1) / RPB;     // 6250
    const int TBc = NBA + NBB;                // 9375

    // ---- workspace (~192 MB) ----
    size_t off = 0;
    auto alloc = [&](size_t bytes) { size_t o = off; off += (bytes + 255) & ~(size_t)255; return o; };
    size_t o_xpbf   = alloc((size_t)nB * DIM * sizeof(u16));          // 102.4 MB
    size_t o_xa1    = alloc((size_t)nA * DIM * sizeof(u16));          // 51.2 MB
    size_t o_cnt    = alloc((size_t)NG * TBc * sizeof(int));          // 0.3 MB
    size_t o_binned = alloc((size_t)NG * TBc * CAP * sizeof(u32));    // 38.4 MB
    (void)ws_size;

    char* ws = (char*)d_ws;
    u16* xpbf   = (u16*)(ws + o_xpbf);
    u16* x_a1   = (u16*)(ws + o_xa1);
    int* cnt    = (int*)(ws + o_cnt);
    u32* binned = (u32*)(ws + o_binned);
    float* x_p2 = (float*)d_out;

    hipMemsetAsync(cnt, 0, (size_t)NG * TBc * sizeof(int), stream);

    long long n4 = (long long)nB * DIM / 4;
    place_conv<<<PC_B, 256, 0, stream>>>(
        e_pa_src, e_pa_dst, e_ap_src, e_ap_dst, cnt, binned,
        TBc, NBA, E1, Etot, x_paper, xpbf, n4);

    // hop 1: paper -> author, out = bf16(relu(sum)); BATCH=16, 32 loads in flight/wave
    gather_hop<16, true><<<NBA, 256, 0, stream>>>(binned, cnt, xpbf, x_a1, TBc, 0, nA);

    // hop 2: author -> paper, out = f32 relu(sum), NT; BATCH=8, 16 loads in flight/wave
    gather_hop<8, false><<<NBB, 256, 0, stream>>>(binned, cnt, x_a1, x_p2, TBc, NBA, nB);
}